// Round 1
// baseline (66.211 us; speedup 1.0000x reference)
//
#include <hip/hip_runtime.h>

// CensoredLoss: inputs
//   d_in[0] = outputs [B=16384, T=512, 4] f32
//   d_in[1] = targets [B=16384, T=512, 5] f32
// output: scalar f32 = -sum(mask*(loss1+loss2)) / count
// mask[b,t] = 1 iff t <= t_max[b], t_max[b] = last t with sum(targets[b,t,:]) > 0.

#define EPSF 1e-8f
#define T_DIM 512

__global__ __launch_bounds__(256) void censored_loss_partial(
    const float* __restrict__ outs,   // [B,T,4]
    const float* __restrict__ tgts,   // [B,T,5]
    float* __restrict__ part_loss,    // [B]
    int* __restrict__ part_cnt)       // [B]
{
    const int b = blockIdx.x;
    const int tid = threadIdx.x;

    float l0 = 0.f, l1 = 0.f;
    int tmax = -1;

    #pragma unroll
    for (int k = 0; k < 2; ++k) {
        const int t = tid + k * 256;
        const size_t bt = (size_t)b * T_DIM + t;
        const float* tg = tgts + bt * 5;
        const float* ou = outs + bt * 4;

        const float t0 = tg[0], t1 = tg[1], t2 = tg[2], t3 = tg[3], t4 = tg[4];
        const float o0 = ou[0], o1 = ou[1], o2 = ou[2], o3 = ou[3];

        const float s = t0 + t1 + t2 + t3 + t4;
        const float cens = 1.0f - (o0 + o1 + o2 + o3);

        const float l = t0 * __logf(cens + EPSF)
                      + t1 * __logf(o0 + EPSF)
                      + t2 * __logf(o1 + EPSF)
                      + t3 * __logf(o2 + EPSF)
                      + t4 * __logf(o3 + EPSF);
        if (k == 0) l0 = l; else l1 = l;
        if (s > 0.f) tmax = t;
    }

    // block-reduce max(tmax) over 256 threads (4 waves of 64)
    #pragma unroll
    for (int off = 32; off > 0; off >>= 1)
        tmax = max(tmax, __shfl_down(tmax, off));

    __shared__ int wmax[4];
    const int wave = tid >> 6, lane = tid & 63;
    if (lane == 0) wmax[wave] = tmax;
    __syncthreads();
    const int bmax = max(max(wmax[0], wmax[1]), max(wmax[2], wmax[3]));

    // masked loss sum: include t <= bmax only
    float sum = 0.f;
    if (tid <= bmax)        sum += l0;
    if (tid + 256 <= bmax)  sum += l1;

    #pragma unroll
    for (int off = 32; off > 0; off >>= 1)
        sum += __shfl_down(sum, off);

    __shared__ float wsum[4];
    if (lane == 0) wsum[wave] = sum;
    __syncthreads();

    if (tid == 0) {
        part_loss[b] = wsum[0] + wsum[1] + wsum[2] + wsum[3];
        part_cnt[b]  = bmax + 1;
    }
}

__global__ __launch_bounds__(256) void censored_loss_finalize(
    const float* __restrict__ part_loss,
    const int* __restrict__ part_cnt,
    float* __restrict__ out, int nblocks)
{
    double ls = 0.0;
    long long cs = 0;
    for (int i = threadIdx.x; i < nblocks; i += 256) {
        ls += (double)part_loss[i];
        cs += (long long)part_cnt[i];
    }
    #pragma unroll
    for (int off = 32; off > 0; off >>= 1) {
        ls += __shfl_down(ls, off);
        cs += __shfl_down(cs, off);
    }
    __shared__ double lw[4];
    __shared__ long long cw[4];
    const int wave = threadIdx.x >> 6, lane = threadIdx.x & 63;
    if (lane == 0) { lw[wave] = ls; cw[wave] = cs; }
    __syncthreads();
    if (threadIdx.x == 0) {
        const double L = lw[0] + lw[1] + lw[2] + lw[3];
        const long long C = cw[0] + cw[1] + cw[2] + cw[3];
        out[0] = (C > 0) ? (float)(-L / (double)C) : 0.0f;
    }
}

extern "C" void kernel_launch(void* const* d_in, const int* in_sizes, int n_in,
                              void* d_out, int out_size, void* d_ws, size_t ws_size,
                              hipStream_t stream) {
    const float* outs = (const float*)d_in[0];
    const float* tgts = (const float*)d_in[1];
    float* out = (float*)d_out;

    const int B = in_sizes[1] / (T_DIM * 5);   // 16384

    float* part_loss = (float*)d_ws;
    int* part_cnt = (int*)((char*)d_ws + (size_t)B * sizeof(float));

    censored_loss_partial<<<B, 256, 0, stream>>>(outs, tgts, part_loss, part_cnt);
    censored_loss_finalize<<<1, 256, 0, stream>>>(part_loss, part_cnt, out, B);
}

// Round 2
// 58.448 us; speedup vs baseline: 1.1328x; 1.1328x over previous
//
#include <hip/hip_runtime.h>

// CensoredLoss:
//   d_in[0] = outputs [B, T=512, 4] f32
//   d_in[1] = targets [B, T=512, 5] f32
// out: scalar f32 = -sum(mask*(loss1+loss2)) / count
// mask[b,t] = 1 iff t <= t_max[b], t_max[b] = last t with sum(targets[b,t,:]) > 0.

#define EPSF 1e-8f
#define T_DIM 512

__global__ __launch_bounds__(256) void censored_loss_partial(
    const float4* __restrict__ outs4,   // [B*T] float4 (outputs, 4 per t)
    const float4* __restrict__ tgts4,   // [B*T*5/4] float4 (targets rows)
    float* __restrict__ part_loss,      // [B]
    int* __restrict__ part_cnt,         // [B]
    int B)
{
    __shared__ float tg_lds[T_DIM * 5];    // 10240 B, one targets row
    __shared__ int wmax[4];
    __shared__ float wsum[4];

    const int tid = threadIdx.x;
    const int wave = tid >> 6, lane = tid & 63;
    const int t0i = tid, t1i = tid + 256;

    for (int b = blockIdx.x; b < B; b += gridDim.x) {
        // ---- stage targets row into LDS (coalesced float4) ----
        const float4* trow = tgts4 + (size_t)b * (T_DIM * 5 / 4);   // 640 float4
        #pragma unroll
        for (int i = tid; i < T_DIM * 5 / 4; i += 256)
            ((float4*)tg_lds)[i] = trow[i];
        __syncthreads();

        // ---- pass 1: per-t target sums -> tmax ----
        float ta[5], tb[5];
        #pragma unroll
        for (int j = 0; j < 5; ++j) ta[j] = tg_lds[t0i * 5 + j];
        #pragma unroll
        for (int j = 0; j < 5; ++j) tb[j] = tg_lds[t1i * 5 + j];

        const float sa = ta[0] + ta[1] + ta[2] + ta[3] + ta[4];
        const float sb = tb[0] + tb[1] + tb[2] + tb[3] + tb[4];

        int tmax = -1;
        if (sa > 0.f) tmax = t0i;
        if (sb > 0.f) tmax = t1i;

        #pragma unroll
        for (int off = 32; off > 0; off >>= 1)
            tmax = max(tmax, __shfl_down(tmax, off));
        if (lane == 0) wmax[wave] = tmax;
        __syncthreads();
        const int bmax = max(max(wmax[0], wmax[1]), max(wmax[2], wmax[3]));

        // ---- pass 2: loss for t <= bmax only (skip masked outputs loads) ----
        float sum = 0.f;
        if (t0i <= bmax) {
            const float4 o = outs4[(size_t)b * T_DIM + t0i];
            const float cens = 1.0f - (o.x + o.y + o.z + o.w);
            sum += ta[0] * __logf(cens + EPSF)
                 + ta[1] * __logf(o.x + EPSF)
                 + ta[2] * __logf(o.y + EPSF)
                 + ta[3] * __logf(o.z + EPSF)
                 + ta[4] * __logf(o.w + EPSF);
        }
        if (t1i <= bmax) {
            const float4 o = outs4[(size_t)b * T_DIM + t1i];
            const float cens = 1.0f - (o.x + o.y + o.z + o.w);
            sum += tb[0] * __logf(cens + EPSF)
                 + tb[1] * __logf(o.x + EPSF)
                 + tb[2] * __logf(o.y + EPSF)
                 + tb[3] * __logf(o.z + EPSF)
                 + tb[4] * __logf(o.w + EPSF);
        }

        #pragma unroll
        for (int off = 32; off > 0; off >>= 1)
            sum += __shfl_down(sum, off);
        if (lane == 0) wsum[wave] = sum;
        __syncthreads();

        if (tid == 0) {
            part_loss[b] = wsum[0] + wsum[1] + wsum[2] + wsum[3];
            part_cnt[b]  = bmax + 1;
        }
        __syncthreads();   // protect LDS before next row's staging
    }
}

__global__ __launch_bounds__(256) void censored_loss_finalize(
    const float* __restrict__ part_loss,
    const int* __restrict__ part_cnt,
    float* __restrict__ out, int nblocks)
{
    double ls = 0.0;
    long long cs = 0;
    for (int i = threadIdx.x; i < nblocks; i += 256) {
        ls += (double)part_loss[i];
        cs += (long long)part_cnt[i];
    }
    #pragma unroll
    for (int off = 32; off > 0; off >>= 1) {
        ls += __shfl_down(ls, off);
        cs += __shfl_down(cs, off);
    }
    __shared__ double lw[4];
    __shared__ long long cw[4];
    const int wave = threadIdx.x >> 6, lane = threadIdx.x & 63;
    if (lane == 0) { lw[wave] = ls; cw[wave] = cs; }
    __syncthreads();
    if (threadIdx.x == 0) {
        const double L = lw[0] + lw[1] + lw[2] + lw[3];
        const long long C = cw[0] + cw[1] + cw[2] + cw[3];
        out[0] = (C > 0) ? (float)(-L / (double)C) : 0.0f;
    }
}

extern "C" void kernel_launch(void* const* d_in, const int* in_sizes, int n_in,
                              void* d_out, int out_size, void* d_ws, size_t ws_size,
                              hipStream_t stream) {
    const float4* outs4 = (const float4*)d_in[0];
    const float4* tgts4 = (const float4*)d_in[1];
    float* out = (float*)d_out;

    const int B = in_sizes[1] / (T_DIM * 5);

    float* part_loss = (float*)d_ws;
    int* part_cnt = (int*)((char*)d_ws + (size_t)B * sizeof(float));

    const int nblocks = (B < 2048) ? B : 2048;
    censored_loss_partial<<<nblocks, 256, 0, stream>>>(outs4, tgts4, part_loss, part_cnt, B);
    censored_loss_finalize<<<1, 256, 0, stream>>>(part_loss, part_cnt, out, B);
}